// Round 18
// baseline (182.727 us; speedup 1.0000x reference)
//
#include <hip/hip_runtime.h>

// GCN 2-layer encoder for MI355X (gfx950) — round 18.
// r17 post-mortem (117.4 best): fill pinned at ~46us for 13 variants;
// signature = WRITE_SIZE 33MB excess = every scattered 2B store dirties a
// full 64B line (random dst, scattered in time). r18: two-phase BINNED fill:
//   Phase A (|| gemm1): edges -> 1568 bucket buffers as packed u32
//     ((d&255)<<16|src), bucket=(d>>8)*8+(tid&7). Concurrent same-bucket
//     writers get ADJACENT positions -> lines fill before eviction (amp ~1x).
//   Phase B (196 blocks, 1 per 256-node range): coalesced bucket reads,
//     LDS-atomic ranks, csr writes into an exclusively-owned 64KB region
//     (L2-resident, single writeback). Emits indeg+dinv -> k_dinv deleted.
//
// Pipeline (6 dispatches):
//   k_init(zero bcur || split W1 || split W2) -> k_gemm1_fillA(MFMA-LDS
//   gemm1 || binned scatter) -> k_fillB -> k_gather_relu -> k_gemm2_mfma
//   -> k_gather64

constexpr int IN_CH  = 128;
constexpr int HID    = 128;
constexpr int OUT_CH = 64;
constexpr int PAD    = 128;   // ELL row stride
constexpr int KSTR   = 40;    // LDS row stride (shorts) for gemm1 staging
constexpr int SB     = 8;     // sub-buckets per 256-node range
constexpr int BCAP   = 768;   // entries per bucket (avg ~383, P(overflow)~0)

using short8v = __attribute__((ext_vector_type(8))) short;
using f32x4v  = __attribute__((ext_vector_type(4))) float;

__device__ __forceinline__ unsigned short f2bf_rne(float f) {
    unsigned int u = __float_as_uint(f);
    u += 0x7FFFu + ((u >> 16) & 1u);
    return (unsigned short)(u >> 16);
}
__device__ __forceinline__ float bf2f(unsigned short h) {
    return __uint_as_float((unsigned int)h << 16);
}

__device__ __forceinline__ bool probe_is64(const int* __restrict__ ei) {
    const int v = ei[2 * (threadIdx.x & 63) + 1];
    return __ballot(v != 0) == 0ull;
}

__device__ __forceinline__ void load_idx4(const int* __restrict__ ei, bool is64,
                                          long long hb, int e0, int n, int* out) {
    const long long p = hb + e0;
    if (is64) {
        if (n == 4 && ((p & 1) == 0)) {
            const int4 a = *reinterpret_cast<const int4*>(ei + 2 * p);
            const int4 b = *reinterpret_cast<const int4*>(ei + 2 * p + 4);
            out[0] = a.x; out[1] = a.z; out[2] = b.x; out[3] = b.z;
        } else {
            for (int j = 0; j < n; ++j) out[j] = ei[2 * (p + j)];
        }
    } else {
        if (n == 4 && ((p & 3) == 0)) {
            const int4 a = *reinterpret_cast<const int4*>(ei + p);
            out[0] = a.x; out[1] = a.y; out[2] = a.z; out[3] = a.w;
        } else {
            for (int j = 0; j < n; ++j) out[j] = ei[p + j];
        }
    }
}

// b==0: zero bcur. b in [1,17): split W1 ([n][k] bf16 hi/lo). [17,25): W2.
__global__ __launch_bounds__(256) void k_init(int* __restrict__ bcur, int nbk,
                                              const float* __restrict__ W1,
                                              const float* __restrict__ W2,
                                              unsigned short* __restrict__ w1th,
                                              unsigned short* __restrict__ w1tl,
                                              unsigned short* __restrict__ w2th,
                                              unsigned short* __restrict__ w2tl) {
    const int b = blockIdx.x;
    if (b == 0) {
        for (int i = threadIdx.x; i < nbk; i += 256) bcur[i] = 0;
    } else if (b < 17) {
        const int i = (b - 1) * 1024 + threadIdx.x * 4;
        const int n = i >> 7, k = i & 127;
#pragma unroll
        for (int j = 0; j < 4; ++j) {
            const float f = W1[(size_t)(k + j) * HID + n];
            const unsigned short h = f2bf_rne(f);
            w1th[n * 128 + k + j] = h;
            w1tl[n * 128 + k + j] = f2bf_rne(f - bf2f(h));
        }
    } else {
        const int i = (b - 17) * 1024 + threadIdx.x * 4;
        const int n = i >> 7, k = i & 127;
#pragma unroll
        for (int j = 0; j < 4; ++j) {
            const float f = W2[(size_t)(k + j) * OUT_CH + n];
            const unsigned short h = f2bf_rne(f);
            w2th[n * 128 + k + j] = h;
            w2tl[n * 128 + k + j] = f2bf_rne(f - bf2f(h));
        }
    }
}

// MFMA GEMM1 with LDS-staged split-W (r17-proven): h1b = x @ W1.
__device__ __forceinline__ void gemm1_mfma_lds(
    const float* __restrict__ X, const unsigned short* __restrict__ w1th,
    const unsigned short* __restrict__ w1tl, unsigned short* __restrict__ Y,
    int M, int blk) {
    __shared__ __align__(16) unsigned short lh[128 * KSTR];
    __shared__ __align__(16) unsigned short ll[128 * KSTR];

    const int tid = threadIdx.x;
    const int wv  = tid >> 6;
    const int ln  = tid & 63;
    const int m16 = ln & 15;
    const int g   = ln >> 4;
    const int arow = blk * 64 + wv * 16 + m16;

    f32x4v acc[8];
#pragma unroll
    for (int n = 0; n < 8; ++n) acc[n] = {0.f, 0.f, 0.f, 0.f};

    for (int k0 = 0; k0 < 128; k0 += 32) {
        __syncthreads();
#pragma unroll
        for (int q = 0; q < 4; ++q) {
            const int id = tid + q * 256;
            if (id < 512) {
                const int n = id >> 2, c = id & 3;
                *reinterpret_cast<short8v*>(&lh[n * KSTR + c * 8]) =
                    *reinterpret_cast<const short8v*>(w1th + n * 128 + k0 + c * 8);
            } else {
                const int id2 = id - 512;
                const int n = id2 >> 2, c = id2 & 3;
                *reinterpret_cast<short8v*>(&ll[n * KSTR + c * 8]) =
                    *reinterpret_cast<const short8v*>(w1tl + n * 128 + k0 + c * 8);
            }
        }
        __syncthreads();

        short8v ah, al;
        if (arow < M) {
            const float4 a0 = *reinterpret_cast<const float4*>(
                X + (size_t)arow * 128 + k0 + g * 8);
            const float4 a1 = *reinterpret_cast<const float4*>(
                X + (size_t)arow * 128 + k0 + g * 8 + 4);
            const float f[8] = {a0.x, a0.y, a0.z, a0.w, a1.x, a1.y, a1.z, a1.w};
#pragma unroll
            for (int e = 0; e < 8; ++e) {
                const unsigned short h = f2bf_rne(f[e]);
                ah[e] = (short)h;
                al[e] = (short)f2bf_rne(f[e] - bf2f(h));
            }
        } else {
#pragma unroll
            for (int e = 0; e < 8; ++e) { ah[e] = 0; al[e] = 0; }
        }

#pragma unroll
        for (int n = 0; n < 8; ++n) {
            const short8v bh = *reinterpret_cast<const short8v*>(
                &lh[(n * 16 + m16) * KSTR + g * 8]);
            const short8v bl = *reinterpret_cast<const short8v*>(
                &ll[(n * 16 + m16) * KSTR + g * 8]);
            acc[n] = __builtin_amdgcn_mfma_f32_16x16x32_bf16(ah, bh, acc[n], 0, 0, 0);
            acc[n] = __builtin_amdgcn_mfma_f32_16x16x32_bf16(al, bh, acc[n], 0, 0, 0);
            acc[n] = __builtin_amdgcn_mfma_f32_16x16x32_bf16(ah, bl, acc[n], 0, 0, 0);
        }
    }

#pragma unroll
    for (int r = 0; r < 4; ++r) {
        const int orow = blk * 64 + wv * 16 + g * 4 + r;
        if (orow < M) {
#pragma unroll
            for (int n = 0; n < 8; ++n)
                Y[(size_t)orow * 128 + n * 16 + m16] = f2bf_rne(acc[n][r]);
        }
    }
}

// Dual-role: blocks [0, gemmBlocks) = MFMA gemm1; rest = phase-A binned
// scatter: bucket=(d>>8)*SB+(tid&7); packed u32 ((d&255)<<16 | src).
__global__ __launch_bounds__(256) void k_gemm1_fillA(
    const float* __restrict__ X, const unsigned short* __restrict__ w1th,
    const unsigned short* __restrict__ w1tl, unsigned short* __restrict__ Y,
    int M, int gemmBlocks, const int* __restrict__ ei,
    int* __restrict__ bcur, unsigned int* __restrict__ bbuf, int E) {
    if ((int)blockIdx.x < gemmBlocks) {
        gemm1_mfma_lds(X, w1th, w1tl, Y, M, blockIdx.x);
        return;
    }
    const bool is64 = probe_is64(ei);
    const int nthr = (gridDim.x - gemmBlocks) * 256;
    const int idx  = (blockIdx.x - gemmBlocks) * 256 + threadIdx.x;
    const int sub  = threadIdx.x & (SB - 1);
    for (int e0 = idx * 4; e0 < E; e0 += nthr * 4) {
        const int n = min(4, E - e0);
        int s[4], d[4];
        load_idx4(ei, is64, 0,            e0, n, s);
        load_idx4(ei, is64, (long long)E, e0, n, d);
        int b[4], pos[4];
        for (int j = 0; j < n; ++j) b[j] = ((d[j] >> 8) << 3) | sub;
        for (int j = 0; j < n; ++j) pos[j] = atomicAdd(&bcur[b[j]], 1);
        for (int j = 0; j < n; ++j)
            if (pos[j] < BCAP)
                bbuf[(size_t)b[j] * BCAP + pos[j]] =
                    ((unsigned int)(d[j] & 255) << 16) | (unsigned int)s[j];
    }
}

// Phase B: block rb owns nodes [rb*256, rb*256+256). Coalesced bucket reads,
// LDS-atomic ranks, csr16 writes into exclusively-owned 64KB region.
// Emits indeg + dinv.
__global__ __launch_bounds__(256) void k_fillB(
    const int* __restrict__ bcur, const unsigned int* __restrict__ bbuf,
    unsigned short* __restrict__ csr16, int* __restrict__ indeg,
    float* __restrict__ dinv, int N) {
    __shared__ int cnt[256];
    const int tid = threadIdx.x;
    const int rb  = blockIdx.x;
    cnt[tid] = 0;
    __syncthreads();

    const int base = rb << 8;
#pragma unroll
    for (int sb = 0; sb < SB; ++sb) {
        const int bk = (rb << 3) | sb;
        int c = bcur[bk];
        if (c > BCAP) c = BCAP;
        const unsigned int* buf = bbuf + (size_t)bk * BCAP;
        for (int i = tid; i < c; i += 256) {
            const unsigned int e = buf[i];
            const int dlow = (int)(e >> 16);
            const int s    = (int)(e & 0xffffu);
            const int r = atomicAdd(&cnt[dlow], 1);
            if (r < PAD)
                csr16[(((size_t)(base + dlow)) << 7) + r] = (unsigned short)s;
        }
    }
    __syncthreads();
    const int node = base + tid;
    if (node < N) {
        const int dg = cnt[tid];
        indeg[node] = dg;
        dinv[node]  = rsqrtf((float)(dg + 1));
    }
}

// aggb[n](bf16) = relu(b1 + h[n]*dinv[n]^2 + sum_e h[s]*dinv[s]*dinv[n])
__global__ __launch_bounds__(256) void k_gather_relu(
    const unsigned short* __restrict__ h, const int* __restrict__ deg,
    const unsigned short* __restrict__ csr16, const float* __restrict__ dinv,
    const float* __restrict__ b, unsigned short* __restrict__ aggb, int N) {
    constexpr int LPN = HID / 4;   // 32
    const int tid  = blockIdx.x * blockDim.x + threadIdx.x;
    const int node = tid / LPN;
    const int lane = tid % LPN;
    if (node >= N) return;

    const float dn = dinv[node];
    float4 acc = reinterpret_cast<const float4*>(b)[lane];
    {
        const float w = dn * dn;  // self loop
        const ushort4 v = *reinterpret_cast<const ushort4*>(h + (size_t)node * HID + lane * 4);
        acc.x = fmaf(bf2f(v.x), w, acc.x); acc.y = fmaf(bf2f(v.y), w, acc.y);
        acc.z = fmaf(bf2f(v.z), w, acc.z); acc.w = fmaf(bf2f(v.w), w, acc.w);
    }

    const unsigned short* row = csr16 + ((size_t)node << 7);
    int dg = deg[node];
    if (dg > PAD) dg = PAD;
    int e = 0;
    for (; e + 1 < dg; e += 2) {
        const int s0 = row[e];
        const int s1 = row[e + 1];
        const float w0 = dinv[s0] * dn;
        const float w1 = dinv[s1] * dn;
        const ushort4 v0 = *reinterpret_cast<const ushort4*>(h + (size_t)s0 * HID + lane * 4);
        const ushort4 v1 = *reinterpret_cast<const ushort4*>(h + (size_t)s1 * HID + lane * 4);
        acc.x = fmaf(bf2f(v0.x), w0, acc.x); acc.y = fmaf(bf2f(v0.y), w0, acc.y);
        acc.z = fmaf(bf2f(v0.z), w0, acc.z); acc.w = fmaf(bf2f(v0.w), w0, acc.w);
        acc.x = fmaf(bf2f(v1.x), w1, acc.x); acc.y = fmaf(bf2f(v1.y), w1, acc.y);
        acc.z = fmaf(bf2f(v1.z), w1, acc.z); acc.w = fmaf(bf2f(v1.w), w1, acc.w);
    }
    if (e < dg) {
        const int s0 = row[e];
        const float w0 = dinv[s0] * dn;
        const ushort4 v0 = *reinterpret_cast<const ushort4*>(h + (size_t)s0 * HID + lane * 4);
        acc.x = fmaf(bf2f(v0.x), w0, acc.x); acc.y = fmaf(bf2f(v0.y), w0, acc.y);
        acc.z = fmaf(bf2f(v0.z), w0, acc.z); acc.w = fmaf(bf2f(v0.w), w0, acc.w);
    }

    ushort4 o;
    o.x = f2bf_rne(fmaxf(acc.x, 0.f));
    o.y = f2bf_rne(fmaxf(acc.y, 0.f));
    o.z = f2bf_rne(fmaxf(acc.z, 0.f));
    o.w = f2bf_rne(fmaxf(acc.w, 0.f));
    *reinterpret_cast<ushort4*>(aggb + (size_t)node * HID + lane * 4) = o;
}

// MFMA GEMM2, LDS-free (proven): h2b = aggb(bf16 exact) @ W2, W2 split.
__global__ __launch_bounds__(256) void k_gemm2_mfma(
    const unsigned short* __restrict__ Xb, const unsigned short* __restrict__ w2th,
    const unsigned short* __restrict__ w2tl, unsigned short* __restrict__ Y, int M) {
    const int tid = threadIdx.x;
    const int wv  = tid >> 6;
    const int ln  = tid & 63;
    const int m16 = ln & 15;
    const int g   = ln >> 4;
    const int arow = blockIdx.x * 64 + wv * 16 + m16;

    f32x4v acc[4];
#pragma unroll
    for (int n = 0; n < 4; ++n) acc[n] = {0.f, 0.f, 0.f, 0.f};

#pragma unroll
    for (int k0 = 0; k0 < 128; k0 += 32) {
        short8v a;
        if (arow < M) {
            a = *reinterpret_cast<const short8v*>(Xb + (size_t)arow * 128 + k0 + g * 8);
        } else {
#pragma unroll
            for (int e = 0; e < 8; ++e) a[e] = 0;
        }
#pragma unroll
        for (int n = 0; n < 4; ++n) {
            const short8v bh = *reinterpret_cast<const short8v*>(
                w2th + (n * 16 + m16) * 128 + k0 + g * 8);
            const short8v bl = *reinterpret_cast<const short8v*>(
                w2tl + (n * 16 + m16) * 128 + k0 + g * 8);
            acc[n] = __builtin_amdgcn_mfma_f32_16x16x32_bf16(a, bh, acc[n], 0, 0, 0);
            acc[n] = __builtin_amdgcn_mfma_f32_16x16x32_bf16(a, bl, acc[n], 0, 0, 0);
        }
    }

#pragma unroll
    for (int r = 0; r < 4; ++r) {
        const int orow = blockIdx.x * 64 + wv * 16 + g * 4 + r;
        if (orow < M) {
#pragma unroll
            for (int n = 0; n < 4; ++n)
                Y[(size_t)orow * 64 + n * 16 + m16] = f2bf_rne(acc[n][r]);
        }
    }
}

// out[n](f32) = b2 + h[n]*dinv[n]^2 + sum_e h[s]*dinv[s]*dinv[n]; ELL csr.
__global__ __launch_bounds__(256) void k_gather64(
    const unsigned short* __restrict__ h, const int* __restrict__ deg,
    const unsigned short* __restrict__ csr16, const float* __restrict__ dinv,
    const float* __restrict__ b, float* __restrict__ out, int N) {
    constexpr int LPN = OUT_CH / 4;   // 16
    const int tid  = blockIdx.x * blockDim.x + threadIdx.x;
    const int node = tid / LPN;
    const int lane = tid % LPN;
    if (node >= N) return;

    const float dn = dinv[node];
    float4 acc = reinterpret_cast<const float4*>(b)[lane];
    {
        const float w = dn * dn;
        const ushort4 v = *reinterpret_cast<const ushort4*>(h + (size_t)node * OUT_CH + lane * 4);
        acc.x = fmaf(bf2f(v.x), w, acc.x); acc.y = fmaf(bf2f(v.y), w, acc.y);
        acc.z = fmaf(bf2f(v.z), w, acc.z); acc.w = fmaf(bf2f(v.w), w, acc.w);
    }

    const unsigned short* row = csr16 + ((size_t)node << 7);
    int dg = deg[node];
    if (dg > PAD) dg = PAD;
    int e = 0;
    for (; e + 1 < dg; e += 2) {
        const int s0 = row[e];
        const int s1 = row[e + 1];
        const float w0 = dinv[s0] * dn;
        const float w1 = dinv[s1] * dn;
        const ushort4 v0 = *reinterpret_cast<const ushort4*>(h + (size_t)s0 * OUT_CH + lane * 4);
        const ushort4 v1 = *reinterpret_cast<const ushort4*>(h + (size_t)s1 * OUT_CH + lane * 4);
        acc.x = fmaf(bf2f(v0.x), w0, acc.x); acc.y = fmaf(bf2f(v0.y), w0, acc.y);
        acc.z = fmaf(bf2f(v0.z), w0, acc.z); acc.w = fmaf(bf2f(v0.w), w0, acc.w);
        acc.x = fmaf(bf2f(v1.x), w1, acc.x); acc.y = fmaf(bf2f(v1.y), w1, acc.y);
        acc.z = fmaf(bf2f(v1.z), w1, acc.z); acc.w = fmaf(bf2f(v1.w), w1, acc.w);
    }
    if (e < dg) {
        const int s0 = row[e];
        const float w0 = dinv[s0] * dn;
        const ushort4 v0 = *reinterpret_cast<const ushort4*>(h + (size_t)s0 * OUT_CH + lane * 4);
        acc.x = fmaf(bf2f(v0.x), w0, acc.x); acc.y = fmaf(bf2f(v0.y), w0, acc.y);
        acc.z = fmaf(bf2f(v0.z), w0, acc.z); acc.w = fmaf(bf2f(v0.w), w0, acc.w);
    }

    reinterpret_cast<float4*>(out + (size_t)node * OUT_CH)[lane] = acc;
}

extern "C" void kernel_launch(void* const* d_in, const int* in_sizes, int n_in,
                              void* d_out, int out_size, void* d_ws, size_t ws_size,
                              hipStream_t stream) {
    const float* x  = (const float*)d_in[0];
    const int*   ei = (const int*)d_in[1];
    const float* W1 = (const float*)d_in[2];
    const float* b1 = (const float*)d_in[3];
    const float* W2 = (const float*)d_in[4];
    const float* b2 = (const float*)d_in[5];
    float* out = (float*)d_out;

    const int N   = in_sizes[0] / IN_CH;   // 50000
    const int E   = in_sizes[1] / 2;       // 600000
    const int NR  = (N + 255) >> 8;        // 196 node ranges
    const int NBK = NR * SB;               // 1568 buckets

    char* wsb = (char*)d_ws;
    size_t off = 0;
    auto alloc = [&](size_t bytes) -> void* {
        void* p = wsb + off;
        off += (bytes + 255) & ~(size_t)255;
        return p;
    };
    int*   bcur  = (int*)alloc((size_t)NBK * sizeof(int));
    int*   indeg = (int*)alloc((size_t)N * sizeof(int));
    float* dinv  = (float*)alloc((size_t)N * sizeof(float));
    unsigned int* bbuf = (unsigned int*)alloc((size_t)NBK * BCAP * sizeof(unsigned int));
    unsigned short* w1th  = (unsigned short*)alloc(128 * 128 * sizeof(unsigned short));
    unsigned short* w1tl  = (unsigned short*)alloc(128 * 128 * sizeof(unsigned short));
    unsigned short* w2th  = (unsigned short*)alloc(64 * 128 * sizeof(unsigned short));
    unsigned short* w2tl  = (unsigned short*)alloc(64 * 128 * sizeof(unsigned short));
    unsigned short* csr16 = (unsigned short*)alloc((size_t)N * PAD * sizeof(unsigned short));
    unsigned short* h1b   = (unsigned short*)alloc((size_t)N * HID * sizeof(unsigned short));
    unsigned short* aggb  = (unsigned short*)alloc((size_t)N * HID * sizeof(unsigned short));
    unsigned short* h2b   = (unsigned short*)alloc((size_t)N * OUT_CH * sizeof(unsigned short));

    auto gs = [](long long n) { return (int)((n + 255) / 256); };

    // zero bcur || split W1 || split W2 (25 blocks)
    k_init<<<25, 256, 0, stream>>>(bcur, NBK, W1, W2, w1th, w1tl, w2th, w2tl);

    // MFMA-LDS gemm1 FIRST || phase-A binned scatter
    const int gemmBlocks = (N + 63) / 64;   // 782
    const int fillBlocks = 512;
    k_gemm1_fillA<<<gemmBlocks + fillBlocks, 256, 0, stream>>>(
        x, w1th, w1tl, h1b, N, gemmBlocks, ei, bcur, bbuf, E);

    // phase B: bucket -> ELL csr, indeg, dinv (1 block per 256-node range)
    k_fillB<<<NR, 256, 0, stream>>>(bcur, bbuf, csr16, indeg, dinv, N);

    // gather1 + bias + ReLU -> bf16 agg (32 lanes/node)
    k_gather_relu<<<gs((long long)N * (HID / 4)), 256, 0, stream>>>(
        h1b, indeg, csr16, dinv, b1, aggb, N);

    // layer-2 transform (LDS-free MFMA)
    k_gemm2_mfma<<<(N + 63) / 64, 256, 0, stream>>>(aggb, w2th, w2tl, h2b, N);

    // final gather -> out (f32)
    k_gather64<<<gs((long long)N * (OUT_CH / 4)), 256, 0, stream>>>(
        h2b, indeg, csr16, dinv, b2, out, N);
}

// Round 19
// 105.061 us; speedup vs baseline: 1.7393x; 1.7393x over previous
//
#include <hip/hip_runtime.h>

// GCN 2-layer encoder for MI355X (gfx950) — round 19.
// r18 post-mortem: 1568-counter global-atomic binning = 100us (383-way
// serialization at coherence point). Phase-B (LDS ranks, owned csr region)
// was cheap. r19: phase A with ZERO global atomics — each fill block owns a
// contiguous 1172-edge slice, bins via LDS cursors into 196 node-ranges
// (avg 6/bin, cap 32), writes its PRIVATE bbuf[block][bin][..] region +
// bcnt[bin][block]. Phase B as r18: per-range block, coalesced counts,
// thread-per-fragment drain, LDS-atomic ranks, owned 64KB csr writes,
// emits indeg+dinv (k_dinv deleted). No buffer pre-zeroing needed.
//
// Pipeline (6 dispatches):
//   k_init(split W1 || split W2) -> k_gemm1_fillA(MFMA-LDS gemm1 || private
//   binning) -> k_fillB -> k_gather_relu -> k_gemm2_mfma -> k_gather64

constexpr int IN_CH  = 128;
constexpr int HID    = 128;
constexpr int OUT_CH = 64;
constexpr int PAD    = 128;   // ELL row stride
constexpr int KSTR   = 40;    // LDS row stride (shorts) for gemm1 staging
constexpr int FB     = 512;   // fill blocks (phase A)
constexpr int FCAP   = 32;    // entries per (block, bin) fragment

using short8v = __attribute__((ext_vector_type(8))) short;
using f32x4v  = __attribute__((ext_vector_type(4))) float;

__device__ __forceinline__ unsigned short f2bf_rne(float f) {
    unsigned int u = __float_as_uint(f);
    u += 0x7FFFu + ((u >> 16) & 1u);
    return (unsigned short)(u >> 16);
}
__device__ __forceinline__ float bf2f(unsigned short h) {
    return __uint_as_float((unsigned int)h << 16);
}

__device__ __forceinline__ bool probe_is64(const int* __restrict__ ei) {
    const int v = ei[2 * (threadIdx.x & 63) + 1];
    return __ballot(v != 0) == 0ull;
}

// split W1 ([n][k] bf16 hi/lo) blocks 0..15; W2 blocks 16..23.
__global__ __launch_bounds__(256) void k_init(const float* __restrict__ W1,
                                              const float* __restrict__ W2,
                                              unsigned short* __restrict__ w1th,
                                              unsigned short* __restrict__ w1tl,
                                              unsigned short* __restrict__ w2th,
                                              unsigned short* __restrict__ w2tl) {
    const int b = blockIdx.x;
    if (b < 16) {
        const int i = b * 1024 + threadIdx.x * 4;
        const int n = i >> 7, k = i & 127;
#pragma unroll
        for (int j = 0; j < 4; ++j) {
            const float f = W1[(size_t)(k + j) * HID + n];
            const unsigned short h = f2bf_rne(f);
            w1th[n * 128 + k + j] = h;
            w1tl[n * 128 + k + j] = f2bf_rne(f - bf2f(h));
        }
    } else {
        const int i = (b - 16) * 1024 + threadIdx.x * 4;
        const int n = i >> 7, k = i & 127;
#pragma unroll
        for (int j = 0; j < 4; ++j) {
            const float f = W2[(size_t)(k + j) * OUT_CH + n];
            const unsigned short h = f2bf_rne(f);
            w2th[n * 128 + k + j] = h;
            w2tl[n * 128 + k + j] = f2bf_rne(f - bf2f(h));
        }
    }
}

// MFMA GEMM1 with LDS-staged split-W (r17-proven): h1b = x @ W1.
__device__ __forceinline__ void gemm1_mfma_lds(
    const float* __restrict__ X, const unsigned short* __restrict__ w1th,
    const unsigned short* __restrict__ w1tl, unsigned short* __restrict__ Y,
    int M, int blk) {
    __shared__ __align__(16) unsigned short lh[128 * KSTR];
    __shared__ __align__(16) unsigned short ll[128 * KSTR];

    const int tid = threadIdx.x;
    const int wv  = tid >> 6;
    const int ln  = tid & 63;
    const int m16 = ln & 15;
    const int g   = ln >> 4;
    const int arow = blk * 64 + wv * 16 + m16;

    f32x4v acc[8];
#pragma unroll
    for (int n = 0; n < 8; ++n) acc[n] = {0.f, 0.f, 0.f, 0.f};

    for (int k0 = 0; k0 < 128; k0 += 32) {
        __syncthreads();
#pragma unroll
        for (int q = 0; q < 4; ++q) {
            const int id = tid + q * 256;
            if (id < 512) {
                const int n = id >> 2, c = id & 3;
                *reinterpret_cast<short8v*>(&lh[n * KSTR + c * 8]) =
                    *reinterpret_cast<const short8v*>(w1th + n * 128 + k0 + c * 8);
            } else {
                const int id2 = id - 512;
                const int n = id2 >> 2, c = id2 & 3;
                *reinterpret_cast<short8v*>(&ll[n * KSTR + c * 8]) =
                    *reinterpret_cast<const short8v*>(w1tl + n * 128 + k0 + c * 8);
            }
        }
        __syncthreads();

        short8v ah, al;
        if (arow < M) {
            const float4 a0 = *reinterpret_cast<const float4*>(
                X + (size_t)arow * 128 + k0 + g * 8);
            const float4 a1 = *reinterpret_cast<const float4*>(
                X + (size_t)arow * 128 + k0 + g * 8 + 4);
            const float f[8] = {a0.x, a0.y, a0.z, a0.w, a1.x, a1.y, a1.z, a1.w};
#pragma unroll
            for (int e = 0; e < 8; ++e) {
                const unsigned short h = f2bf_rne(f[e]);
                ah[e] = (short)h;
                al[e] = (short)f2bf_rne(f[e] - bf2f(h));
            }
        } else {
#pragma unroll
            for (int e = 0; e < 8; ++e) { ah[e] = 0; al[e] = 0; }
        }

#pragma unroll
        for (int n = 0; n < 8; ++n) {
            const short8v bh = *reinterpret_cast<const short8v*>(
                &lh[(n * 16 + m16) * KSTR + g * 8]);
            const short8v bl = *reinterpret_cast<const short8v*>(
                &ll[(n * 16 + m16) * KSTR + g * 8]);
            acc[n] = __builtin_amdgcn_mfma_f32_16x16x32_bf16(ah, bh, acc[n], 0, 0, 0);
            acc[n] = __builtin_amdgcn_mfma_f32_16x16x32_bf16(al, bh, acc[n], 0, 0, 0);
            acc[n] = __builtin_amdgcn_mfma_f32_16x16x32_bf16(ah, bl, acc[n], 0, 0, 0);
        }
    }

#pragma unroll
    for (int r = 0; r < 4; ++r) {
        const int orow = blk * 64 + wv * 16 + g * 4 + r;
        if (orow < M) {
#pragma unroll
            for (int n = 0; n < 8; ++n)
                Y[(size_t)orow * 128 + n * 16 + m16] = f2bf_rne(acc[n][r]);
        }
    }
}

// Dual-role: blocks [0, gemmBlocks) = MFMA gemm1; blocks [gemmBlocks,+FB) =
// phase-A private binning (LDS cursors, NO global atomics).
__global__ __launch_bounds__(256) void k_gemm1_fillA(
    const float* __restrict__ X, const unsigned short* __restrict__ w1th,
    const unsigned short* __restrict__ w1tl, unsigned short* __restrict__ Y,
    int M, int gemmBlocks, const int* __restrict__ ei,
    unsigned int* __restrict__ bbuf, int* __restrict__ bcnt,
    int E, int TILE, int NR) {
    if ((int)blockIdx.x < gemmBlocks) {
        gemm1_mfma_lds(X, w1th, w1tl, Y, M, blockIdx.x);
        return;
    }
    __shared__ int cnt[256];
    const int tid = threadIdx.x;
    const int b   = blockIdx.x - gemmBlocks;
    cnt[tid] = 0;
    __syncthreads();

    const bool is64 = probe_is64(ei);
    const int base = b * TILE;
    const int end  = min(base + TILE, E);
    unsigned int* __restrict__ myb = bbuf + (size_t)b * NR * FCAP;
    for (int e = base + tid; e < end; e += 256) {
        int s, d;
        if (is64) { s = ei[2 * e]; d = ei[2 * (E + e)]; }
        else      { s = ei[e];     d = ei[E + e]; }
        const int bin = d >> 8;
        const int pos = atomicAdd(&cnt[bin], 1);   // LDS atomic
        if (pos < FCAP)
            myb[bin * FCAP + pos] =
                ((unsigned int)(d & 255) << 16) | (unsigned int)s;
    }
    __syncthreads();
    if (tid < NR) bcnt[tid * FB + b] = cnt[tid];
}

// Phase B: block r owns nodes [r*256, r*256+256). Thread t drains fragments
// of source blocks t and t+256; LDS-atomic ranks; owned csr region writes.
// Emits indeg + dinv.
__global__ __launch_bounds__(256) void k_fillB(
    const int* __restrict__ bcnt, const unsigned int* __restrict__ bbuf,
    unsigned short* __restrict__ csr16, int* __restrict__ indeg,
    float* __restrict__ dinv, int N, int NR) {
    __shared__ int cnt2[256];
    __shared__ int cA[FB];
    const int tid = threadIdx.x;
    const int r   = blockIdx.x;
    cnt2[tid] = 0;
    cA[tid]       = bcnt[r * FB + tid];
    cA[tid + 256] = bcnt[r * FB + tid + 256];
    __syncthreads();

    const int base = r << 8;
#pragma unroll
    for (int q = 0; q < 2; ++q) {
        const int sb = tid + q * 256;
        int c = cA[sb];
        if (c > FCAP) c = FCAP;
        const unsigned int* frag = bbuf + ((size_t)sb * NR + r) * FCAP;
        for (int i = 0; i < c; ++i) {
            const unsigned int e = frag[i];
            const int dlow = (int)(e >> 16);
            const int s    = (int)(e & 0xffffu);
            const int rk = atomicAdd(&cnt2[dlow], 1);
            if (rk < PAD)
                csr16[(((size_t)(base + dlow)) << 7) + rk] = (unsigned short)s;
        }
    }
    __syncthreads();
    const int node = base + tid;
    if (node < N) {
        const int dg = cnt2[tid];
        indeg[node] = dg;
        dinv[node]  = rsqrtf((float)(dg + 1));
    }
}

// aggb[n](bf16) = relu(b1 + h[n]*dinv[n]^2 + sum_e h[s]*dinv[s]*dinv[n])
__global__ __launch_bounds__(256) void k_gather_relu(
    const unsigned short* __restrict__ h, const int* __restrict__ deg,
    const unsigned short* __restrict__ csr16, const float* __restrict__ dinv,
    const float* __restrict__ b, unsigned short* __restrict__ aggb, int N) {
    constexpr int LPN = HID / 4;   // 32
    const int tid  = blockIdx.x * blockDim.x + threadIdx.x;
    const int node = tid / LPN;
    const int lane = tid % LPN;
    if (node >= N) return;

    const float dn = dinv[node];
    float4 acc = reinterpret_cast<const float4*>(b)[lane];
    {
        const float w = dn * dn;  // self loop
        const ushort4 v = *reinterpret_cast<const ushort4*>(h + (size_t)node * HID + lane * 4);
        acc.x = fmaf(bf2f(v.x), w, acc.x); acc.y = fmaf(bf2f(v.y), w, acc.y);
        acc.z = fmaf(bf2f(v.z), w, acc.z); acc.w = fmaf(bf2f(v.w), w, acc.w);
    }

    const unsigned short* row = csr16 + ((size_t)node << 7);
    int dg = deg[node];
    if (dg > PAD) dg = PAD;
    int e = 0;
    for (; e + 1 < dg; e += 2) {
        const int s0 = row[e];
        const int s1 = row[e + 1];
        const float w0 = dinv[s0] * dn;
        const float w1 = dinv[s1] * dn;
        const ushort4 v0 = *reinterpret_cast<const ushort4*>(h + (size_t)s0 * HID + lane * 4);
        const ushort4 v1 = *reinterpret_cast<const ushort4*>(h + (size_t)s1 * HID + lane * 4);
        acc.x = fmaf(bf2f(v0.x), w0, acc.x); acc.y = fmaf(bf2f(v0.y), w0, acc.y);
        acc.z = fmaf(bf2f(v0.z), w0, acc.z); acc.w = fmaf(bf2f(v0.w), w0, acc.w);
        acc.x = fmaf(bf2f(v1.x), w1, acc.x); acc.y = fmaf(bf2f(v1.y), w1, acc.y);
        acc.z = fmaf(bf2f(v1.z), w1, acc.z); acc.w = fmaf(bf2f(v1.w), w1, acc.w);
    }
    if (e < dg) {
        const int s0 = row[e];
        const float w0 = dinv[s0] * dn;
        const ushort4 v0 = *reinterpret_cast<const ushort4*>(h + (size_t)s0 * HID + lane * 4);
        acc.x = fmaf(bf2f(v0.x), w0, acc.x); acc.y = fmaf(bf2f(v0.y), w0, acc.y);
        acc.z = fmaf(bf2f(v0.z), w0, acc.z); acc.w = fmaf(bf2f(v0.w), w0, acc.w);
    }

    ushort4 o;
    o.x = f2bf_rne(fmaxf(acc.x, 0.f));
    o.y = f2bf_rne(fmaxf(acc.y, 0.f));
    o.z = f2bf_rne(fmaxf(acc.z, 0.f));
    o.w = f2bf_rne(fmaxf(acc.w, 0.f));
    *reinterpret_cast<ushort4*>(aggb + (size_t)node * HID + lane * 4) = o;
}

// MFMA GEMM2, LDS-free (proven): h2b = aggb(bf16 exact) @ W2, W2 split.
__global__ __launch_bounds__(256) void k_gemm2_mfma(
    const unsigned short* __restrict__ Xb, const unsigned short* __restrict__ w2th,
    const unsigned short* __restrict__ w2tl, unsigned short* __restrict__ Y, int M) {
    const int tid = threadIdx.x;
    const int wv  = tid >> 6;
    const int ln  = tid & 63;
    const int m16 = ln & 15;
    const int g   = ln >> 4;
    const int arow = blockIdx.x * 64 + wv * 16 + m16;

    f32x4v acc[4];
#pragma unroll
    for (int n = 0; n < 4; ++n) acc[n] = {0.f, 0.f, 0.f, 0.f};

#pragma unroll
    for (int k0 = 0; k0 < 128; k0 += 32) {
        short8v a;
        if (arow < M) {
            a = *reinterpret_cast<const short8v*>(Xb + (size_t)arow * 128 + k0 + g * 8);
        } else {
#pragma unroll
            for (int e = 0; e < 8; ++e) a[e] = 0;
        }
#pragma unroll
        for (int n = 0; n < 4; ++n) {
            const short8v bh = *reinterpret_cast<const short8v*>(
                w2th + (n * 16 + m16) * 128 + k0 + g * 8);
            const short8v bl = *reinterpret_cast<const short8v*>(
                w2tl + (n * 16 + m16) * 128 + k0 + g * 8);
            acc[n] = __builtin_amdgcn_mfma_f32_16x16x32_bf16(a, bh, acc[n], 0, 0, 0);
            acc[n] = __builtin_amdgcn_mfma_f32_16x16x32_bf16(a, bl, acc[n], 0, 0, 0);
        }
    }

#pragma unroll
    for (int r = 0; r < 4; ++r) {
        const int orow = blockIdx.x * 64 + wv * 16 + g * 4 + r;
        if (orow < M) {
#pragma unroll
            for (int n = 0; n < 4; ++n)
                Y[(size_t)orow * 64 + n * 16 + m16] = f2bf_rne(acc[n][r]);
        }
    }
}

// out[n](f32) = b2 + h[n]*dinv[n]^2 + sum_e h[s]*dinv[s]*dinv[n]; ELL csr.
__global__ __launch_bounds__(256) void k_gather64(
    const unsigned short* __restrict__ h, const int* __restrict__ deg,
    const unsigned short* __restrict__ csr16, const float* __restrict__ dinv,
    const float* __restrict__ b, float* __restrict__ out, int N) {
    constexpr int LPN = OUT_CH / 4;   // 16
    const int tid  = blockIdx.x * blockDim.x + threadIdx.x;
    const int node = tid / LPN;
    const int lane = tid % LPN;
    if (node >= N) return;

    const float dn = dinv[node];
    float4 acc = reinterpret_cast<const float4*>(b)[lane];
    {
        const float w = dn * dn;
        const ushort4 v = *reinterpret_cast<const ushort4*>(h + (size_t)node * OUT_CH + lane * 4);
        acc.x = fmaf(bf2f(v.x), w, acc.x); acc.y = fmaf(bf2f(v.y), w, acc.y);
        acc.z = fmaf(bf2f(v.z), w, acc.z); acc.w = fmaf(bf2f(v.w), w, acc.w);
    }

    const unsigned short* row = csr16 + ((size_t)node << 7);
    int dg = deg[node];
    if (dg > PAD) dg = PAD;
    int e = 0;
    for (; e + 1 < dg; e += 2) {
        const int s0 = row[e];
        const int s1 = row[e + 1];
        const float w0 = dinv[s0] * dn;
        const float w1 = dinv[s1] * dn;
        const ushort4 v0 = *reinterpret_cast<const ushort4*>(h + (size_t)s0 * OUT_CH + lane * 4);
        const ushort4 v1 = *reinterpret_cast<const ushort4*>(h + (size_t)s1 * OUT_CH + lane * 4);
        acc.x = fmaf(bf2f(v0.x), w0, acc.x); acc.y = fmaf(bf2f(v0.y), w0, acc.y);
        acc.z = fmaf(bf2f(v0.z), w0, acc.z); acc.w = fmaf(bf2f(v0.w), w0, acc.w);
        acc.x = fmaf(bf2f(v1.x), w1, acc.x); acc.y = fmaf(bf2f(v1.y), w1, acc.y);
        acc.z = fmaf(bf2f(v1.z), w1, acc.z); acc.w = fmaf(bf2f(v1.w), w1, acc.w);
    }
    if (e < dg) {
        const int s0 = row[e];
        const float w0 = dinv[s0] * dn;
        const ushort4 v0 = *reinterpret_cast<const ushort4*>(h + (size_t)s0 * OUT_CH + lane * 4);
        acc.x = fmaf(bf2f(v0.x), w0, acc.x); acc.y = fmaf(bf2f(v0.y), w0, acc.y);
        acc.z = fmaf(bf2f(v0.z), w0, acc.z); acc.w = fmaf(bf2f(v0.w), w0, acc.w);
    }

    reinterpret_cast<float4*>(out + (size_t)node * OUT_CH)[lane] = acc;
}

extern "C" void kernel_launch(void* const* d_in, const int* in_sizes, int n_in,
                              void* d_out, int out_size, void* d_ws, size_t ws_size,
                              hipStream_t stream) {
    const float* x  = (const float*)d_in[0];
    const int*   ei = (const int*)d_in[1];
    const float* W1 = (const float*)d_in[2];
    const float* b1 = (const float*)d_in[3];
    const float* W2 = (const float*)d_in[4];
    const float* b2 = (const float*)d_in[5];
    float* out = (float*)d_out;

    const int N    = in_sizes[0] / IN_CH;    // 50000
    const int E    = in_sizes[1] / 2;        // 600000
    const int NR   = (N + 255) >> 8;         // 196 node ranges
    const int TILE = (E + FB - 1) / FB;      // 1172 edges per fill block

    char* wsb = (char*)d_ws;
    size_t off = 0;
    auto alloc = [&](size_t bytes) -> void* {
        void* p = wsb + off;
        off += (bytes + 255) & ~(size_t)255;
        return p;
    };
    int*   indeg = (int*)alloc((size_t)N * sizeof(int));
    float* dinv  = (float*)alloc((size_t)N * sizeof(float));
    int*   bcnt  = (int*)alloc((size_t)NR * FB * sizeof(int));
    unsigned int* bbuf = (unsigned int*)alloc((size_t)FB * NR * FCAP * sizeof(unsigned int));
    unsigned short* w1th  = (unsigned short*)alloc(128 * 128 * sizeof(unsigned short));
    unsigned short* w1tl  = (unsigned short*)alloc(128 * 128 * sizeof(unsigned short));
    unsigned short* w2th  = (unsigned short*)alloc(64 * 128 * sizeof(unsigned short));
    unsigned short* w2tl  = (unsigned short*)alloc(64 * 128 * sizeof(unsigned short));
    unsigned short* csr16 = (unsigned short*)alloc((size_t)N * PAD * sizeof(unsigned short));
    unsigned short* h1b   = (unsigned short*)alloc((size_t)N * HID * sizeof(unsigned short));
    unsigned short* aggb  = (unsigned short*)alloc((size_t)N * HID * sizeof(unsigned short));
    unsigned short* h2b   = (unsigned short*)alloc((size_t)N * OUT_CH * sizeof(unsigned short));

    auto gs = [](long long n) { return (int)((n + 255) / 256); };

    // split W1 || split W2 (24 blocks; nothing needs zeroing)
    k_init<<<24, 256, 0, stream>>>(W1, W2, w1th, w1tl, w2th, w2tl);

    // MFMA-LDS gemm1 FIRST || phase-A private binning (no global atomics)
    const int gemmBlocks = (N + 63) / 64;   // 782
    k_gemm1_fillA<<<gemmBlocks + FB, 256, 0, stream>>>(
        x, w1th, w1tl, h1b, N, gemmBlocks, ei, bbuf, bcnt, E, TILE, NR);

    // phase B: fragments -> ELL csr + indeg + dinv
    k_fillB<<<NR, 256, 0, stream>>>(bcnt, bbuf, csr16, indeg, dinv, N, NR);

    // gather1 + bias + ReLU -> bf16 agg (32 lanes/node)
    k_gather_relu<<<gs((long long)N * (HID / 4)), 256, 0, stream>>>(
        h1b, indeg, csr16, dinv, b1, aggb, N);

    // layer-2 transform (LDS-free MFMA)
    k_gemm2_mfma<<<(N + 63) / 64, 256, 0, stream>>>(aggb, w2th, w2tl, h2b, N);

    // final gather -> out (f32)
    k_gather64<<<gs((long long)N * (OUT_CH / 4)), 256, 0, stream>>>(
        h2b, indeg, csr16, dinv, b2, out, N);
}

// Round 20
// 103.066 us; speedup vs baseline: 1.7729x; 1.0194x over previous
//
#include <hip/hip_runtime.h>

// GCN 2-layer encoder for MI355X (gfx950) — round 20.
// r19 (105.1 best): private-LDS binned fill landed; top-5 now harness fills
// (all our kernels < 40us). r20 tuning pass:
//   (a) FB 512->784 fill blocks (TILE 766): shrink binning role if it is
//       the fused-dispatch pole;
//   (b) fillB drains fragments with uint4 (4 edges/load);
//   (c) gather_relu 4-edge unroll (more loads in flight).
// Pre-commit: if total moves < +-3us, remaining stages are at their
// demonstrated floors (gathers ~6.2 TB/s, fill contention-free, GEMMs on
// matrix pipe) -> declare roofline.
//
// Pipeline (6 dispatches):
//   k_init(split W1 || split W2) -> k_gemm1_fillA(MFMA-LDS gemm1 || private
//   binning) -> k_fillB -> k_gather_relu -> k_gemm2_mfma -> k_gather64

constexpr int IN_CH  = 128;
constexpr int HID    = 128;
constexpr int OUT_CH = 64;
constexpr int PAD    = 128;   // ELL row stride
constexpr int KSTR   = 40;    // LDS row stride (shorts) for gemm1 staging
constexpr int FB     = 784;   // fill blocks (phase A)
constexpr int FCAP   = 32;    // entries per (block, bin) fragment

using short8v = __attribute__((ext_vector_type(8))) short;
using f32x4v  = __attribute__((ext_vector_type(4))) float;

__device__ __forceinline__ unsigned short f2bf_rne(float f) {
    unsigned int u = __float_as_uint(f);
    u += 0x7FFFu + ((u >> 16) & 1u);
    return (unsigned short)(u >> 16);
}
__device__ __forceinline__ float bf2f(unsigned short h) {
    return __uint_as_float((unsigned int)h << 16);
}

__device__ __forceinline__ bool probe_is64(const int* __restrict__ ei) {
    const int v = ei[2 * (threadIdx.x & 63) + 1];
    return __ballot(v != 0) == 0ull;
}

// split W1 ([n][k] bf16 hi/lo) blocks 0..15; W2 blocks 16..23.
__global__ __launch_bounds__(256) void k_init(const float* __restrict__ W1,
                                              const float* __restrict__ W2,
                                              unsigned short* __restrict__ w1th,
                                              unsigned short* __restrict__ w1tl,
                                              unsigned short* __restrict__ w2th,
                                              unsigned short* __restrict__ w2tl) {
    const int b = blockIdx.x;
    if (b < 16) {
        const int i = b * 1024 + threadIdx.x * 4;
        const int n = i >> 7, k = i & 127;
#pragma unroll
        for (int j = 0; j < 4; ++j) {
            const float f = W1[(size_t)(k + j) * HID + n];
            const unsigned short h = f2bf_rne(f);
            w1th[n * 128 + k + j] = h;
            w1tl[n * 128 + k + j] = f2bf_rne(f - bf2f(h));
        }
    } else {
        const int i = (b - 16) * 1024 + threadIdx.x * 4;
        const int n = i >> 7, k = i & 127;
#pragma unroll
        for (int j = 0; j < 4; ++j) {
            const float f = W2[(size_t)(k + j) * OUT_CH + n];
            const unsigned short h = f2bf_rne(f);
            w2th[n * 128 + k + j] = h;
            w2tl[n * 128 + k + j] = f2bf_rne(f - bf2f(h));
        }
    }
}

// MFMA GEMM1 with LDS-staged split-W (r17-proven): h1b = x @ W1.
__device__ __forceinline__ void gemm1_mfma_lds(
    const float* __restrict__ X, const unsigned short* __restrict__ w1th,
    const unsigned short* __restrict__ w1tl, unsigned short* __restrict__ Y,
    int M, int blk) {
    __shared__ __align__(16) unsigned short lh[128 * KSTR];
    __shared__ __align__(16) unsigned short ll[128 * KSTR];

    const int tid = threadIdx.x;
    const int wv  = tid >> 6;
    const int ln  = tid & 63;
    const int m16 = ln & 15;
    const int g   = ln >> 4;
    const int arow = blk * 64 + wv * 16 + m16;

    f32x4v acc[8];
#pragma unroll
    for (int n = 0; n < 8; ++n) acc[n] = {0.f, 0.f, 0.f, 0.f};

    for (int k0 = 0; k0 < 128; k0 += 32) {
        __syncthreads();
#pragma unroll
        for (int q = 0; q < 4; ++q) {
            const int id = tid + q * 256;
            if (id < 512) {
                const int n = id >> 2, c = id & 3;
                *reinterpret_cast<short8v*>(&lh[n * KSTR + c * 8]) =
                    *reinterpret_cast<const short8v*>(w1th + n * 128 + k0 + c * 8);
            } else {
                const int id2 = id - 512;
                const int n = id2 >> 2, c = id2 & 3;
                *reinterpret_cast<short8v*>(&ll[n * KSTR + c * 8]) =
                    *reinterpret_cast<const short8v*>(w1tl + n * 128 + k0 + c * 8);
            }
        }
        __syncthreads();

        short8v ah, al;
        if (arow < M) {
            const float4 a0 = *reinterpret_cast<const float4*>(
                X + (size_t)arow * 128 + k0 + g * 8);
            const float4 a1 = *reinterpret_cast<const float4*>(
                X + (size_t)arow * 128 + k0 + g * 8 + 4);
            const float f[8] = {a0.x, a0.y, a0.z, a0.w, a1.x, a1.y, a1.z, a1.w};
#pragma unroll
            for (int e = 0; e < 8; ++e) {
                const unsigned short h = f2bf_rne(f[e]);
                ah[e] = (short)h;
                al[e] = (short)f2bf_rne(f[e] - bf2f(h));
            }
        } else {
#pragma unroll
            for (int e = 0; e < 8; ++e) { ah[e] = 0; al[e] = 0; }
        }

#pragma unroll
        for (int n = 0; n < 8; ++n) {
            const short8v bh = *reinterpret_cast<const short8v*>(
                &lh[(n * 16 + m16) * KSTR + g * 8]);
            const short8v bl = *reinterpret_cast<const short8v*>(
                &ll[(n * 16 + m16) * KSTR + g * 8]);
            acc[n] = __builtin_amdgcn_mfma_f32_16x16x32_bf16(ah, bh, acc[n], 0, 0, 0);
            acc[n] = __builtin_amdgcn_mfma_f32_16x16x32_bf16(al, bh, acc[n], 0, 0, 0);
            acc[n] = __builtin_amdgcn_mfma_f32_16x16x32_bf16(ah, bl, acc[n], 0, 0, 0);
        }
    }

#pragma unroll
    for (int r = 0; r < 4; ++r) {
        const int orow = blk * 64 + wv * 16 + g * 4 + r;
        if (orow < M) {
#pragma unroll
            for (int n = 0; n < 8; ++n)
                Y[(size_t)orow * 128 + n * 16 + m16] = f2bf_rne(acc[n][r]);
        }
    }
}

// Dual-role: blocks [0, gemmBlocks) = MFMA gemm1; blocks [gemmBlocks,+FB) =
// phase-A private binning (LDS cursors, NO global atomics).
__global__ __launch_bounds__(256) void k_gemm1_fillA(
    const float* __restrict__ X, const unsigned short* __restrict__ w1th,
    const unsigned short* __restrict__ w1tl, unsigned short* __restrict__ Y,
    int M, int gemmBlocks, const int* __restrict__ ei,
    unsigned int* __restrict__ bbuf, int* __restrict__ bcnt,
    int E, int TILE, int NR) {
    if ((int)blockIdx.x < gemmBlocks) {
        gemm1_mfma_lds(X, w1th, w1tl, Y, M, blockIdx.x);
        return;
    }
    __shared__ int cnt[256];
    const int tid = threadIdx.x;
    const int b   = blockIdx.x - gemmBlocks;
    cnt[tid] = 0;
    __syncthreads();

    const bool is64 = probe_is64(ei);
    const int base = b * TILE;
    const int end  = min(base + TILE, E);
    unsigned int* __restrict__ myb = bbuf + (size_t)b * NR * FCAP;
    for (int e = base + tid; e < end; e += 256) {
        int s, d;
        if (is64) { s = ei[2 * e]; d = ei[2 * (E + e)]; }
        else      { s = ei[e];     d = ei[E + e]; }
        const int bin = d >> 8;
        const int pos = atomicAdd(&cnt[bin], 1);   // LDS atomic
        if (pos < FCAP)
            myb[bin * FCAP + pos] =
                ((unsigned int)(d & 255) << 16) | (unsigned int)s;
    }
    __syncthreads();
    if (tid < NR) bcnt[tid * FB + b] = cnt[tid];
}

// Phase B: block r owns nodes [r*256, r*256+256). Threads drain fragments of
// source blocks (uint4 reads, 4 edges/load); LDS-atomic ranks; owned csr
// region writes. Emits indeg + dinv.
__global__ __launch_bounds__(256) void k_fillB(
    const int* __restrict__ bcnt, const unsigned int* __restrict__ bbuf,
    unsigned short* __restrict__ csr16, int* __restrict__ indeg,
    float* __restrict__ dinv, int N, int NR) {
    __shared__ int cnt2[256];
    __shared__ int cA[FB];
    const int tid = threadIdx.x;
    const int r   = blockIdx.x;
    cnt2[tid] = 0;
    for (int sb = tid; sb < FB; sb += 256) cA[sb] = bcnt[r * FB + sb];
    __syncthreads();

    const int base = r << 8;
    for (int sb = tid; sb < FB; sb += 256) {
        int c = cA[sb];
        if (c > FCAP) c = FCAP;
        const uint4* frag4 = reinterpret_cast<const uint4*>(
            bbuf + ((size_t)sb * NR + r) * FCAP);
        for (int i = 0; i < c; i += 4) {
            const uint4 v = frag4[i >> 2];
            const unsigned int ev[4] = {v.x, v.y, v.z, v.w};
            const int n = min(4, c - i);
            for (int j = 0; j < n; ++j) {
                const unsigned int e = ev[j];
                const int dlow = (int)(e >> 16);
                const int s    = (int)(e & 0xffffu);
                const int rk = atomicAdd(&cnt2[dlow], 1);
                if (rk < PAD)
                    csr16[(((size_t)(base + dlow)) << 7) + rk] = (unsigned short)s;
            }
        }
    }
    __syncthreads();
    const int node = base + tid;
    if (node < N) {
        const int dg = cnt2[tid];
        indeg[node] = dg;
        dinv[node]  = rsqrtf((float)(dg + 1));
    }
}

// aggb[n](bf16) = relu(b1 + h[n]*dinv[n]^2 + sum_e h[s]*dinv[s]*dinv[n])
// 32 lanes/node, 4-edge unroll, ELL csr.
__global__ __launch_bounds__(256) void k_gather_relu(
    const unsigned short* __restrict__ h, const int* __restrict__ deg,
    const unsigned short* __restrict__ csr16, const float* __restrict__ dinv,
    const float* __restrict__ b, unsigned short* __restrict__ aggb, int N) {
    constexpr int LPN = HID / 4;   // 32
    const int tid  = blockIdx.x * blockDim.x + threadIdx.x;
    const int node = tid / LPN;
    const int lane = tid % LPN;
    if (node >= N) return;

    const float dn = dinv[node];
    float4 acc = reinterpret_cast<const float4*>(b)[lane];
    {
        const float w = dn * dn;  // self loop
        const ushort4 v = *reinterpret_cast<const ushort4*>(h + (size_t)node * HID + lane * 4);
        acc.x = fmaf(bf2f(v.x), w, acc.x); acc.y = fmaf(bf2f(v.y), w, acc.y);
        acc.z = fmaf(bf2f(v.z), w, acc.z); acc.w = fmaf(bf2f(v.w), w, acc.w);
    }

    const unsigned short* row = csr16 + ((size_t)node << 7);
    int dg = deg[node];
    if (dg > PAD) dg = PAD;
    int e = 0;
    for (; e + 3 < dg; e += 4) {
        const int s0 = row[e], s1 = row[e + 1], s2 = row[e + 2], s3 = row[e + 3];
        const float w0 = dinv[s0] * dn;
        const float w1 = dinv[s1] * dn;
        const float w2 = dinv[s2] * dn;
        const float w3 = dinv[s3] * dn;
        const ushort4 v0 = *reinterpret_cast<const ushort4*>(h + (size_t)s0 * HID + lane * 4);
        const ushort4 v1 = *reinterpret_cast<const ushort4*>(h + (size_t)s1 * HID + lane * 4);
        const ushort4 v2 = *reinterpret_cast<const ushort4*>(h + (size_t)s2 * HID + lane * 4);
        const ushort4 v3 = *reinterpret_cast<const ushort4*>(h + (size_t)s3 * HID + lane * 4);
        acc.x = fmaf(bf2f(v0.x), w0, acc.x); acc.y = fmaf(bf2f(v0.y), w0, acc.y);
        acc.z = fmaf(bf2f(v0.z), w0, acc.z); acc.w = fmaf(bf2f(v0.w), w0, acc.w);
        acc.x = fmaf(bf2f(v1.x), w1, acc.x); acc.y = fmaf(bf2f(v1.y), w1, acc.y);
        acc.z = fmaf(bf2f(v1.z), w1, acc.z); acc.w = fmaf(bf2f(v1.w), w1, acc.w);
        acc.x = fmaf(bf2f(v2.x), w2, acc.x); acc.y = fmaf(bf2f(v2.y), w2, acc.y);
        acc.z = fmaf(bf2f(v2.z), w2, acc.z); acc.w = fmaf(bf2f(v2.w), w2, acc.w);
        acc.x = fmaf(bf2f(v3.x), w3, acc.x); acc.y = fmaf(bf2f(v3.y), w3, acc.y);
        acc.z = fmaf(bf2f(v3.z), w3, acc.z); acc.w = fmaf(bf2f(v3.w), w3, acc.w);
    }
    for (; e < dg; ++e) {
        const int s0 = row[e];
        const float w0 = dinv[s0] * dn;
        const ushort4 v0 = *reinterpret_cast<const ushort4*>(h + (size_t)s0 * HID + lane * 4);
        acc.x = fmaf(bf2f(v0.x), w0, acc.x); acc.y = fmaf(bf2f(v0.y), w0, acc.y);
        acc.z = fmaf(bf2f(v0.z), w0, acc.z); acc.w = fmaf(bf2f(v0.w), w0, acc.w);
    }

    ushort4 o;
    o.x = f2bf_rne(fmaxf(acc.x, 0.f));
    o.y = f2bf_rne(fmaxf(acc.y, 0.f));
    o.z = f2bf_rne(fmaxf(acc.z, 0.f));
    o.w = f2bf_rne(fmaxf(acc.w, 0.f));
    *reinterpret_cast<ushort4*>(aggb + (size_t)node * HID + lane * 4) = o;
}

// MFMA GEMM2, LDS-free (proven): h2b = aggb(bf16 exact) @ W2, W2 split.
__global__ __launch_bounds__(256) void k_gemm2_mfma(
    const unsigned short* __restrict__ Xb, const unsigned short* __restrict__ w2th,
    const unsigned short* __restrict__ w2tl, unsigned short* __restrict__ Y, int M) {
    const int tid = threadIdx.x;
    const int wv  = tid >> 6;
    const int ln  = tid & 63;
    const int m16 = ln & 15;
    const int g   = ln >> 4;
    const int arow = blockIdx.x * 64 + wv * 16 + m16;

    f32x4v acc[4];
#pragma unroll
    for (int n = 0; n < 4; ++n) acc[n] = {0.f, 0.f, 0.f, 0.f};

#pragma unroll
    for (int k0 = 0; k0 < 128; k0 += 32) {
        short8v a;
        if (arow < M) {
            a = *reinterpret_cast<const short8v*>(Xb + (size_t)arow * 128 + k0 + g * 8);
        } else {
#pragma unroll
            for (int e = 0; e < 8; ++e) a[e] = 0;
        }
#pragma unroll
        for (int n = 0; n < 4; ++n) {
            const short8v bh = *reinterpret_cast<const short8v*>(
                w2th + (n * 16 + m16) * 128 + k0 + g * 8);
            const short8v bl = *reinterpret_cast<const short8v*>(
                w2tl + (n * 16 + m16) * 128 + k0 + g * 8);
            acc[n] = __builtin_amdgcn_mfma_f32_16x16x32_bf16(a, bh, acc[n], 0, 0, 0);
            acc[n] = __builtin_amdgcn_mfma_f32_16x16x32_bf16(a, bl, acc[n], 0, 0, 0);
        }
    }

#pragma unroll
    for (int r = 0; r < 4; ++r) {
        const int orow = blockIdx.x * 64 + wv * 16 + g * 4 + r;
        if (orow < M) {
#pragma unroll
            for (int n = 0; n < 4; ++n)
                Y[(size_t)orow * 64 + n * 16 + m16] = f2bf_rne(acc[n][r]);
        }
    }
}

// out[n](f32) = b2 + h[n]*dinv[n]^2 + sum_e h[s]*dinv[s]*dinv[n]; ELL csr.
__global__ __launch_bounds__(256) void k_gather64(
    const unsigned short* __restrict__ h, const int* __restrict__ deg,
    const unsigned short* __restrict__ csr16, const float* __restrict__ dinv,
    const float* __restrict__ b, float* __restrict__ out, int N) {
    constexpr int LPN = OUT_CH / 4;   // 16
    const int tid  = blockIdx.x * blockDim.x + threadIdx.x;
    const int node = tid / LPN;
    const int lane = tid % LPN;
    if (node >= N) return;

    const float dn = dinv[node];
    float4 acc = reinterpret_cast<const float4*>(b)[lane];
    {
        const float w = dn * dn;
        const ushort4 v = *reinterpret_cast<const ushort4*>(h + (size_t)node * OUT_CH + lane * 4);
        acc.x = fmaf(bf2f(v.x), w, acc.x); acc.y = fmaf(bf2f(v.y), w, acc.y);
        acc.z = fmaf(bf2f(v.z), w, acc.z); acc.w = fmaf(bf2f(v.w), w, acc.w);
    }

    const unsigned short* row = csr16 + ((size_t)node << 7);
    int dg = deg[node];
    if (dg > PAD) dg = PAD;
    int e = 0;
    for (; e + 3 < dg; e += 4) {
        const int s0 = row[e], s1 = row[e + 1], s2 = row[e + 2], s3 = row[e + 3];
        const float w0 = dinv[s0] * dn;
        const float w1 = dinv[s1] * dn;
        const float w2 = dinv[s2] * dn;
        const float w3 = dinv[s3] * dn;
        const ushort4 v0 = *reinterpret_cast<const ushort4*>(h + (size_t)s0 * OUT_CH + lane * 4);
        const ushort4 v1 = *reinterpret_cast<const ushort4*>(h + (size_t)s1 * OUT_CH + lane * 4);
        const ushort4 v2 = *reinterpret_cast<const ushort4*>(h + (size_t)s2 * OUT_CH + lane * 4);
        const ushort4 v3 = *reinterpret_cast<const ushort4*>(h + (size_t)s3 * OUT_CH + lane * 4);
        acc.x = fmaf(bf2f(v0.x), w0, acc.x); acc.y = fmaf(bf2f(v0.y), w0, acc.y);
        acc.z = fmaf(bf2f(v0.z), w0, acc.z); acc.w = fmaf(bf2f(v0.w), w0, acc.w);
        acc.x = fmaf(bf2f(v1.x), w1, acc.x); acc.y = fmaf(bf2f(v1.y), w1, acc.y);
        acc.z = fmaf(bf2f(v1.z), w1, acc.z); acc.w = fmaf(bf2f(v1.w), w1, acc.w);
        acc.x = fmaf(bf2f(v2.x), w2, acc.x); acc.y = fmaf(bf2f(v2.y), w2, acc.y);
        acc.z = fmaf(bf2f(v2.z), w2, acc.z); acc.w = fmaf(bf2f(v2.w), w2, acc.w);
        acc.x = fmaf(bf2f(v3.x), w3, acc.x); acc.y = fmaf(bf2f(v3.y), w3, acc.y);
        acc.z = fmaf(bf2f(v3.z), w3, acc.z); acc.w = fmaf(bf2f(v3.w), w3, acc.w);
    }
    for (; e < dg; ++e) {
        const int s0 = row[e];
        const float w0 = dinv[s0] * dn;
        const ushort4 v0 = *reinterpret_cast<const ushort4*>(h + (size_t)s0 * OUT_CH + lane * 4);
        acc.x = fmaf(bf2f(v0.x), w0, acc.x); acc.y = fmaf(bf2f(v0.y), w0, acc.y);
        acc.z = fmaf(bf2f(v0.z), w0, acc.z); acc.w = fmaf(bf2f(v0.w), w0, acc.w);
    }

    reinterpret_cast<float4*>(out + (size_t)node * OUT_CH)[lane] = acc;
}

extern "C" void kernel_launch(void* const* d_in, const int* in_sizes, int n_in,
                              void* d_out, int out_size, void* d_ws, size_t ws_size,
                              hipStream_t stream) {
    const float* x  = (const float*)d_in[0];
    const int*   ei = (const int*)d_in[1];
    const float* W1 = (const float*)d_in[2];
    const float* b1 = (const float*)d_in[3];
    const float* W2 = (const float*)d_in[4];
    const float* b2 = (const float*)d_in[5];
    float* out = (float*)d_out;

    const int N    = in_sizes[0] / IN_CH;    // 50000
    const int E    = in_sizes[1] / 2;        // 600000
    const int NR   = (N + 255) >> 8;         // 196 node ranges
    const int TILE = (E + FB - 1) / FB;      // 766 edges per fill block

    char* wsb = (char*)d_ws;
    size_t off = 0;
    auto alloc = [&](size_t bytes) -> void* {
        void* p = wsb + off;
        off += (bytes + 255) & ~(size_t)255;
        return p;
    };
    int*   indeg = (int*)alloc((size_t)N * sizeof(int));
    float* dinv  = (float*)alloc((size_t)N * sizeof(float));
    int*   bcnt  = (int*)alloc((size_t)NR * FB * sizeof(int));
    unsigned int* bbuf = (unsigned int*)alloc((size_t)FB * NR * FCAP * sizeof(unsigned int));
    unsigned short* w1th  = (unsigned short*)alloc(128 * 128 * sizeof(unsigned short));
    unsigned short* w1tl  = (unsigned short*)alloc(128 * 128 * sizeof(unsigned short));
    unsigned short* w2th  = (unsigned short*)alloc(64 * 128 * sizeof(unsigned short));
    unsigned short* w2tl  = (unsigned short*)alloc(64 * 128 * sizeof(unsigned short));
    unsigned short* csr16 = (unsigned short*)alloc((size_t)N * PAD * sizeof(unsigned short));
    unsigned short* h1b   = (unsigned short*)alloc((size_t)N * HID * sizeof(unsigned short));
    unsigned short* aggb  = (unsigned short*)alloc((size_t)N * HID * sizeof(unsigned short));
    unsigned short* h2b   = (unsigned short*)alloc((size_t)N * OUT_CH * sizeof(unsigned short));

    auto gs = [](long long n) { return (int)((n + 255) / 256); };

    // split W1 || split W2 (24 blocks; nothing needs zeroing)
    k_init<<<24, 256, 0, stream>>>(W1, W2, w1th, w1tl, w2th, w2tl);

    // MFMA-LDS gemm1 FIRST || phase-A private binning (no global atomics)
    const int gemmBlocks = (N + 63) / 64;   // 782
    k_gemm1_fillA<<<gemmBlocks + FB, 256, 0, stream>>>(
        x, w1th, w1tl, h1b, N, gemmBlocks, ei, bbuf, bcnt, E, TILE, NR);

    // phase B: fragments -> ELL csr + indeg + dinv
    k_fillB<<<NR, 256, 0, stream>>>(bcnt, bbuf, csr16, indeg, dinv, N, NR);

    // gather1 + bias + ReLU -> bf16 agg (32 lanes/node)
    k_gather_relu<<<gs((long long)N * (HID / 4)), 256, 0, stream>>>(
        h1b, indeg, csr16, dinv, b1, aggb, N);

    // layer-2 transform (LDS-free MFMA)
    k_gemm2_mfma<<<(N + 63) / 64, 256, 0, stream>>>(aggb, w2th, w2tl, h2b, N);

    // final gather -> out (f32)
    k_gather64<<<gs((long long)N * (OUT_CH / 4)), 256, 0, stream>>>(
        h2b, indeg, csr16, dinv, b2, out, N);
}